// Round 3
// baseline (887.283 us; speedup 1.0000x reference)
//
#include <hip/hip_runtime.h>
#include <hip/hip_bf16.h>
#include <cstdint>
#include <cstddef>

// ---- problem constants (DeepSeek-V3 MoE config) ----
#define T_TOK 1024
#define H_DIM 1024
#define I_DIM 704
#define E_NUM 64
#define TOPK 8
#define NGRP 8
#define GSIZE 8
#define TOPKG 4
#define SI_DIM 1408
#define RSCALE 2.5f
#define NSLOT (T_TOK * TOPK)   // 8192

#define AP 72            // LDS row pitch in bf16 elems (144B rows -> 2-way max bank aliasing, free)

typedef short bf16x8 __attribute__((ext_vector_type(8)));
typedef float f32x4 __attribute__((ext_vector_type(4)));

__device__ inline unsigned pk2(float x, float y) {
    __hip_bfloat162 h2 = __float22bfloat162_rn(make_float2(x, y));
    unsigned u; __builtin_memcpy(&u, &h2, 4); return u;
}
__device__ inline unsigned short bf1(float x) {
    __hip_bfloat16 h = __float2bfloat16(x);
    unsigned short u; __builtin_memcpy(&u, &h, 2); return u;
}
__device__ inline float bf2f(unsigned short u) {
    unsigned v = ((unsigned)u) << 16; float f; __builtin_memcpy(&f, &v, 4); return f;
}

// ---------------- fp32 -> bf16 streaming conversion ----------------
__global__ __launch_bounds__(256) void cvt_kernel(const float* __restrict__ in,
                                                  unsigned short* __restrict__ out, int n8)
{
    int stride = gridDim.x * blockDim.x;
    for (int i = blockIdx.x * blockDim.x + threadIdx.x; i < n8; i += stride) {
        float4 a = ((const float4*)in)[2 * i];
        float4 b = ((const float4*)in)[2 * i + 1];
        uint4 o = make_uint4(pk2(a.x, a.y), pk2(a.z, a.w), pk2(b.x, b.y), pk2(b.z, b.w));
        ((uint4*)out)[i] = o;
    }
}

// ---------------- routing ----------------
__global__ __launch_bounds__(64) void route_kernel(
    const float* __restrict__ x, const float* __restrict__ gw, const float* __restrict__ gb,
    int* __restrict__ counts, int* __restrict__ tk_idx, float* __restrict__ tk_w)
{
    const int t = blockIdx.x;
    __shared__ float xs[H_DIM];
    __shared__ float raw[E_NUM];
    __shared__ float sc[E_NUM];
    __shared__ float masked[E_NUM];
    __shared__ float gsc[NGRP];
    const int tid = threadIdx.x;

    const float4* xrow = (const float4*)(x + (size_t)t * H_DIM);
    for (int i = tid; i < H_DIM / 4; i += 64) ((float4*)xs)[i] = xrow[i];
    __syncthreads();

    float a = 0.f;
    const float* w = gw + (size_t)tid * H_DIM;
    for (int h = 0; h < H_DIM; h += 4) {
        float4 w4 = *(const float4*)(w + h);
        a += xs[h] * w4.x + xs[h+1] * w4.y + xs[h+2] * w4.z + xs[h+3] * w4.w;
    }
    float s = 1.f / (1.f + expf(-a));
    raw[tid] = s;
    sc[tid] = s + gb[tid];
    __syncthreads();

    if (tid == 0) {
        for (int g = 0; g < NGRP; ++g) {
            float m1 = -1e30f, m2 = -1e30f;
            for (int j = 0; j < GSIZE; ++j) {
                float v = sc[g * GSIZE + j];
                if (v > m1) { m2 = m1; m1 = v; }
                else if (v > m2) { m2 = v; }
            }
            gsc[g] = m1 + m2;
        }
        bool gsel[NGRP];
        for (int g = 0; g < NGRP; ++g) gsel[g] = false;
        for (int k = 0; k < TOPKG; ++k) {
            int best = -1; float bv = -1e30f;
            for (int g = 0; g < NGRP; ++g)
                if (!gsel[g] && gsc[g] > bv) { bv = gsc[g]; best = g; }
            gsel[best] = true;
        }
        for (int e = 0; e < E_NUM; ++e)
            masked[e] = gsel[e / GSIZE] ? sc[e] : 0.0f;
        int idx[TOPK];
        float wsum = 0.f;
        for (int k = 0; k < TOPK; ++k) {
            int best = 0; float bv = -1e30f;
            for (int e = 0; e < E_NUM; ++e)
                if (masked[e] > bv) { bv = masked[e]; best = e; }
            masked[best] = -1e30f;
            idx[k] = best;
            wsum += raw[best];
        }
        float inv = RSCALE / (wsum + 1e-20f);
        for (int k = 0; k < TOPK; ++k) {
            tk_idx[t * TOPK + k] = idx[k];
            tk_w[t * TOPK + k] = raw[idx[k]] * inv;
            atomicAdd(&counts[idx[k]], 1);
        }
    }
}

__global__ void zero_kernel(int* counts, int* fillc)
{
    int i = threadIdx.x;
    if (i < E_NUM) { counts[i] = 0; fillc[i] = 0; }
}

__global__ void scan_kernel(const int* __restrict__ counts, int* __restrict__ offs)
{
    if (threadIdx.x == 0) {
        int acc = 0;
        for (int e = 0; e < E_NUM; ++e) { offs[e] = acc; acc += counts[e]; }
    }
}

__global__ void fill_kernel(const int* __restrict__ tk_idx, const float* __restrict__ tk_w,
                            const int* __restrict__ offs, int* __restrict__ fillc,
                            int* __restrict__ tok_list, float* __restrict__ w_list,
                            int* __restrict__ tk_slot)
{
    int t = blockIdx.x * blockDim.x + threadIdx.x;
    if (t >= T_TOK) return;
    for (int k = 0; k < TOPK; ++k) {
        int e = tk_idx[t * TOPK + k];
        int pos = offs[e] + atomicAdd(&fillc[e], 1);
        tok_list[pos] = t;
        w_list[pos] = tk_w[t * TOPK + k];
        tk_slot[t * TOPK + k] = pos;
    }
}

// ---------------- routed gate/up: MFMA, SwiGLU + combine-weight fused, bf16 act out ----------------
template<bool PRE>
__global__ __launch_bounds__(256) void gateup_routed_mfma(
    const float* __restrict__ x, const unsigned short* __restrict__ xb,
    const float* __restrict__ Wg, const float* __restrict__ Wu,
    const unsigned short* __restrict__ bWg, const unsigned short* __restrict__ bWu,
    const int* __restrict__ offs, const int* __restrict__ counts,
    const int* __restrict__ tok_list, const float* __restrict__ w_list,
    unsigned short* __restrict__ act)
{
    const int e = blockIdx.z;
    const int cnt = counts[e];
    const int m0 = blockIdx.y * 128;
    if (m0 >= cnt) return;
    const int off = offs[e];
    const int n0 = blockIdx.x * 64;

    __shared__ __align__(16) unsigned short As[128 * AP];
    __shared__ __align__(16) unsigned short Bg[64 * AP];
    __shared__ __align__(16) unsigned short Bu[64 * AP];
    __shared__ int toks[128];
    __shared__ float wts[128];

    const int tid = threadIdx.x;
    if (tid < 128) {
        int s = m0 + tid;
        toks[tid] = (s < cnt) ? tok_list[off + s] : -1;
        wts[tid]  = (s < cnt) ? w_list[off + s] : 0.f;
    }
    __syncthreads();

    const int lane = tid & 63;
    const int wv = tid >> 6;
    const int lr = lane & 15;
    const int lq = lane >> 4;

    f32x4 accg[2][4], accu[2][4];
    #pragma unroll
    for (int i = 0; i < 2; ++i)
        #pragma unroll
        for (int j = 0; j < 4; ++j) {
            accg[i][j] = (f32x4){0.f, 0.f, 0.f, 0.f};
            accu[i][j] = (f32x4){0.f, 0.f, 0.f, 0.f};
        }

    // PRE staging mapping: 16B (8 bf16) chunks
    const int cr = tid >> 3;          // 0..31
    const int cc8 = (tid & 7) * 8;    // bf16 col within 64
    // fallback fp32 mapping
    const int ar = tid >> 4;
    const int ac = (tid & 15) * 4;

    for (int k0 = 0; k0 < H_DIM; k0 += 64) {
        if (PRE) {
            #pragma unroll
            for (int p = 0; p < 4; ++p) {
                int r = cr + p * 32;
                int tkn = toks[r];
                uint4 v = make_uint4(0u, 0u, 0u, 0u);
                if (tkn >= 0) v = *(const uint4*)(xb + (size_t)tkn * H_DIM + k0 + cc8);
                *(uint4*)&As[r * AP + cc8] = v;
            }
            const unsigned short* bg0 = bWg + ((size_t)e * I_DIM + n0) * H_DIM + k0 + cc8;
            const unsigned short* bu0 = bWu + ((size_t)e * I_DIM + n0) * H_DIM + k0 + cc8;
            #pragma unroll
            for (int p = 0; p < 2; ++p) {
                int r = cr + p * 32;
                *(uint4*)&Bg[r * AP + cc8] = *(const uint4*)(bg0 + (size_t)r * H_DIM);
                *(uint4*)&Bu[r * AP + cc8] = *(const uint4*)(bu0 + (size_t)r * H_DIM);
            }
        } else {
            #pragma unroll
            for (int p = 0; p < 8; ++p) {
                int r = ar + p * 16;
                int tkn = toks[r];
                float4 v = make_float4(0.f, 0.f, 0.f, 0.f);
                if (tkn >= 0) v = *(const float4*)(x + (size_t)tkn * H_DIM + k0 + ac);
                *(uint2*)&As[r * AP + ac] = make_uint2(pk2(v.x, v.y), pk2(v.z, v.w));
            }
            const float* wgp = Wg + ((size_t)e * I_DIM + n0) * H_DIM;
            const float* wup = Wu + ((size_t)e * I_DIM + n0) * H_DIM;
            #pragma unroll
            for (int p = 0; p < 4; ++p) {
                int r = ar + p * 16;
                float4 g = *(const float4*)(wgp + (size_t)r * H_DIM + k0 + ac);
                *(uint2*)&Bg[r * AP + ac] = make_uint2(pk2(g.x, g.y), pk2(g.z, g.w));
                float4 u = *(const float4*)(wup + (size_t)r * H_DIM + k0 + ac);
                *(uint2*)&Bu[r * AP + ac] = make_uint2(pk2(u.x, u.y), pk2(u.z, u.w));
            }
        }
        __syncthreads();
        #pragma unroll
        for (int ks = 0; ks < 2; ++ks) {
            bf16x8 a0 = *(const bf16x8*)&As[(wv * 32 + lr) * AP + ks * 32 + lq * 8];
            bf16x8 a1 = *(const bf16x8*)&As[(wv * 32 + 16 + lr) * AP + ks * 32 + lq * 8];
            #pragma unroll
            for (int nj = 0; nj < 4; ++nj) {
                bf16x8 bg = *(const bf16x8*)&Bg[(nj * 16 + lr) * AP + ks * 32 + lq * 8];
                bf16x8 bu = *(const bf16x8*)&Bu[(nj * 16 + lr) * AP + ks * 32 + lq * 8];
                accg[0][nj] = __builtin_amdgcn_mfma_f32_16x16x32_bf16(a0, bg, accg[0][nj], 0, 0, 0);
                accg[1][nj] = __builtin_amdgcn_mfma_f32_16x16x32_bf16(a1, bg, accg[1][nj], 0, 0, 0);
                accu[0][nj] = __builtin_amdgcn_mfma_f32_16x16x32_bf16(a0, bu, accu[0][nj], 0, 0, 0);
                accu[1][nj] = __builtin_amdgcn_mfma_f32_16x16x32_bf16(a1, bu, accu[1][nj], 0, 0, 0);
            }
        }
        __syncthreads();
    }

    #pragma unroll
    for (int mi = 0; mi < 2; ++mi) {
        #pragma unroll
        for (int r = 0; r < 4; ++r) {
            int srow = wv * 32 + mi * 16 + lq * 4 + r;
            if (m0 + srow < cnt) {
                float w = wts[srow];
                unsigned short* ap = act + (size_t)(off + m0 + srow) * I_DIM + n0 + lr;
                #pragma unroll
                for (int nj = 0; nj < 4; ++nj) {
                    float g = accg[mi][nj][r];
                    float u = accu[mi][nj][r];
                    float a = w * (g / (1.f + __expf(-g))) * u;
                    ap[nj * 16] = bf1(a);
                }
            }
        }
    }
}

// ---------------- routed down proj: MFMA, per-slot bf16 stores (no atomics) ----------------
template<bool PRE>
__global__ __launch_bounds__(256) void down_routed_mfma(
    const unsigned short* __restrict__ act,
    const float* __restrict__ Wd, const unsigned short* __restrict__ bWd,
    const int* __restrict__ offs, const int* __restrict__ counts,
    unsigned short* __restrict__ dslot)
{
    const int e = blockIdx.z;
    const int cnt = counts[e];
    const int m0 = blockIdx.y * 128;
    if (m0 >= cnt) return;
    const int off = offs[e];
    const int n0 = blockIdx.x * 64;

    __shared__ __align__(16) unsigned short As[128 * AP];
    __shared__ __align__(16) unsigned short Bs[64 * AP];

    const int tid = threadIdx.x;
    const int lane = tid & 63;
    const int wv = tid >> 6;
    const int lr = lane & 15;
    const int lq = lane >> 4;

    f32x4 acc[2][4];
    #pragma unroll
    for (int i = 0; i < 2; ++i)
        #pragma unroll
        for (int j = 0; j < 4; ++j)
            acc[i][j] = (f32x4){0.f, 0.f, 0.f, 0.f};

    const int cr = tid >> 3;
    const int cc8 = (tid & 7) * 8;
    const int ar = tid >> 4;
    const int ac = (tid & 15) * 4;

    const unsigned short* ap0 = act + (size_t)(off + m0) * I_DIM;

    for (int k0 = 0; k0 < I_DIM; k0 += 64) {
        #pragma unroll
        for (int p = 0; p < 4; ++p) {
            int r = cr + p * 32;
            uint4 v = make_uint4(0u, 0u, 0u, 0u);
            if (m0 + r < cnt) v = *(const uint4*)(ap0 + (size_t)r * I_DIM + k0 + cc8);
            *(uint4*)&As[r * AP + cc8] = v;
        }
        if (PRE) {
            const unsigned short* bd0 = bWd + ((size_t)e * H_DIM + n0) * I_DIM + k0 + cc8;
            #pragma unroll
            for (int p = 0; p < 2; ++p) {
                int r = cr + p * 32;
                *(uint4*)&Bs[r * AP + cc8] = *(const uint4*)(bd0 + (size_t)r * I_DIM);
            }
        } else {
            const float* wdp = Wd + ((size_t)e * H_DIM + n0) * I_DIM;
            #pragma unroll
            for (int p = 0; p < 4; ++p) {
                int r = ar + p * 16;
                float4 w4 = *(const float4*)(wdp + (size_t)r * I_DIM + k0 + ac);
                *(uint2*)&Bs[r * AP + ac] = make_uint2(pk2(w4.x, w4.y), pk2(w4.z, w4.w));
            }
        }
        __syncthreads();
        #pragma unroll
        for (int ks = 0; ks < 2; ++ks) {
            bf16x8 a0 = *(const bf16x8*)&As[(wv * 32 + lr) * AP + ks * 32 + lq * 8];
            bf16x8 a1 = *(const bf16x8*)&As[(wv * 32 + 16 + lr) * AP + ks * 32 + lq * 8];
            #pragma unroll
            for (int nj = 0; nj < 4; ++nj) {
                bf16x8 b = *(const bf16x8*)&Bs[(nj * 16 + lr) * AP + ks * 32 + lq * 8];
                acc[0][nj] = __builtin_amdgcn_mfma_f32_16x16x32_bf16(a0, b, acc[0][nj], 0, 0, 0);
                acc[1][nj] = __builtin_amdgcn_mfma_f32_16x16x32_bf16(a1, b, acc[1][nj], 0, 0, 0);
            }
        }
        __syncthreads();
    }

    #pragma unroll
    for (int mi = 0; mi < 2; ++mi) {
        #pragma unroll
        for (int r = 0; r < 4; ++r) {
            int srow = wv * 32 + mi * 16 + lq * 4 + r;
            if (m0 + srow < cnt) {
                unsigned short* dp = dslot + (size_t)(off + m0 + srow) * H_DIM + n0 + lr;
                #pragma unroll
                for (int nj = 0; nj < 4; ++nj)
                    dp[nj * 16] = bf1(acc[mi][nj][r]);
            }
        }
    }
}

// ---------------- shared expert gate/up: MFMA dense, bf16 sact out ----------------
template<bool PRE>
__global__ __launch_bounds__(256) void gateup_shared_mfma(
    const float* __restrict__ x, const unsigned short* __restrict__ xb,
    const float* __restrict__ Sg, const float* __restrict__ Su,
    const unsigned short* __restrict__ bSg, const unsigned short* __restrict__ bSu,
    unsigned short* __restrict__ sact)
{
    const int m0 = blockIdx.y * 128;
    const int n0 = blockIdx.x * 64;

    __shared__ __align__(16) unsigned short As[128 * AP];
    __shared__ __align__(16) unsigned short Bg[64 * AP];
    __shared__ __align__(16) unsigned short Bu[64 * AP];

    const int tid = threadIdx.x;
    const int lane = tid & 63;
    const int wv = tid >> 6;
    const int lr = lane & 15;
    const int lq = lane >> 4;

    f32x4 accg[2][4], accu[2][4];
    #pragma unroll
    for (int i = 0; i < 2; ++i)
        #pragma unroll
        for (int j = 0; j < 4; ++j) {
            accg[i][j] = (f32x4){0.f, 0.f, 0.f, 0.f};
            accu[i][j] = (f32x4){0.f, 0.f, 0.f, 0.f};
        }

    const int cr = tid >> 3;
    const int cc8 = (tid & 7) * 8;
    const int ar = tid >> 4;
    const int ac = (tid & 15) * 4;

    for (int k0 = 0; k0 < H_DIM; k0 += 64) {
        if (PRE) {
            #pragma unroll
            for (int p = 0; p < 4; ++p) {
                int r = cr + p * 32;
                *(uint4*)&As[r * AP + cc8] = *(const uint4*)(xb + (size_t)(m0 + r) * H_DIM + k0 + cc8);
            }
            const unsigned short* bg0 = bSg + (size_t)n0 * H_DIM + k0 + cc8;
            const unsigned short* bu0 = bSu + (size_t)n0 * H_DIM + k0 + cc8;
            #pragma unroll
            for (int p = 0; p < 2; ++p) {
                int r = cr + p * 32;
                *(uint4*)&Bg[r * AP + cc8] = *(const uint4*)(bg0 + (size_t)r * H_DIM);
                *(uint4*)&Bu[r * AP + cc8] = *(const uint4*)(bu0 + (size_t)r * H_DIM);
            }
        } else {
            #pragma unroll
            for (int p = 0; p < 8; ++p) {
                int r = ar + p * 16;
                float4 v = *(const float4*)(x + (size_t)(m0 + r) * H_DIM + k0 + ac);
                *(uint2*)&As[r * AP + ac] = make_uint2(pk2(v.x, v.y), pk2(v.z, v.w));
            }
            const float* gp = Sg + (size_t)n0 * H_DIM;
            const float* up = Su + (size_t)n0 * H_DIM;
            #pragma unroll
            for (int p = 0; p < 4; ++p) {
                int r = ar + p * 16;
                float4 g = *(const float4*)(gp + (size_t)r * H_DIM + k0 + ac);
                *(uint2*)&Bg[r * AP + ac] = make_uint2(pk2(g.x, g.y), pk2(g.z, g.w));
                float4 u = *(const float4*)(up + (size_t)r * H_DIM + k0 + ac);
                *(uint2*)&Bu[r * AP + ac] = make_uint2(pk2(u.x, u.y), pk2(u.z, u.w));
            }
        }
        __syncthreads();
        #pragma unroll
        for (int ks = 0; ks < 2; ++ks) {
            bf16x8 a0 = *(const bf16x8*)&As[(wv * 32 + lr) * AP + ks * 32 + lq * 8];
            bf16x8 a1 = *(const bf16x8*)&As[(wv * 32 + 16 + lr) * AP + ks * 32 + lq * 8];
            #pragma unroll
            for (int nj = 0; nj < 4; ++nj) {
                bf16x8 bg = *(const bf16x8*)&Bg[(nj * 16 + lr) * AP + ks * 32 + lq * 8];
                bf16x8 bu = *(const bf16x8*)&Bu[(nj * 16 + lr) * AP + ks * 32 + lq * 8];
                accg[0][nj] = __builtin_amdgcn_mfma_f32_16x16x32_bf16(a0, bg, accg[0][nj], 0, 0, 0);
                accg[1][nj] = __builtin_amdgcn_mfma_f32_16x16x32_bf16(a1, bg, accg[1][nj], 0, 0, 0);
                accu[0][nj] = __builtin_amdgcn_mfma_f32_16x16x32_bf16(a0, bu, accu[0][nj], 0, 0, 0);
                accu[1][nj] = __builtin_amdgcn_mfma_f32_16x16x32_bf16(a1, bu, accu[1][nj], 0, 0, 0);
            }
        }
        __syncthreads();
    }

    #pragma unroll
    for (int mi = 0; mi < 2; ++mi) {
        #pragma unroll
        for (int r = 0; r < 4; ++r) {
            int trow = m0 + wv * 32 + mi * 16 + lq * 4 + r;
            unsigned short* sp = sact + (size_t)trow * SI_DIM + n0 + lr;
            #pragma unroll
            for (int nj = 0; nj < 4; ++nj) {
                float g = accg[mi][nj][r];
                float u = accu[mi][nj][r];
                float a = (g / (1.f + __expf(-g))) * u;
                sp[nj * 16] = bf1(a);
            }
        }
    }
}

// ---------------- shared expert down proj: MFMA dense, writes out (fp32) ----------------
template<bool PRE>
__global__ __launch_bounds__(256) void down_shared_mfma(
    const unsigned short* __restrict__ sact,
    const float* __restrict__ Sd, const unsigned short* __restrict__ bSd,
    float* __restrict__ out)
{
    const int m0 = blockIdx.y * 128;
    const int n0 = blockIdx.x * 64;

    __shared__ __align__(16) unsigned short As[128 * AP];
    __shared__ __align__(16) unsigned short Bs[64 * AP];

    const int tid = threadIdx.x;
    const int lane = tid & 63;
    const int wv = tid >> 6;
    const int lr = lane & 15;
    const int lq = lane >> 4;

    f32x4 acc[2][4];
    #pragma unroll
    for (int i = 0; i < 2; ++i)
        #pragma unroll
        for (int j = 0; j < 4; ++j)
            acc[i][j] = (f32x4){0.f, 0.f, 0.f, 0.f};

    const int cr = tid >> 3;
    const int cc8 = (tid & 7) * 8;
    const int ar = tid >> 4;
    const int ac = (tid & 15) * 4;

    for (int k0 = 0; k0 < SI_DIM; k0 += 64) {
        #pragma unroll
        for (int p = 0; p < 4; ++p) {
            int r = cr + p * 32;
            *(uint4*)&As[r * AP + cc8] = *(const uint4*)(sact + (size_t)(m0 + r) * SI_DIM + k0 + cc8);
        }
        if (PRE) {
            const unsigned short* bd0 = bSd + (size_t)n0 * SI_DIM + k0 + cc8;
            #pragma unroll
            for (int p = 0; p < 2; ++p) {
                int r = cr + p * 32;
                *(uint4*)&Bs[r * AP + cc8] = *(const uint4*)(bd0 + (size_t)r * SI_DIM);
            }
        } else {
            const float* wp = Sd + (size_t)n0 * SI_DIM;
            #pragma unroll
            for (int p = 0; p < 4; ++p) {
                int r = ar + p * 16;
                float4 w4 = *(const float4*)(wp + (size_t)r * SI_DIM + k0 + ac);
                *(uint2*)&Bs[r * AP + ac] = make_uint2(pk2(w4.x, w4.y), pk2(w4.z, w4.w));
            }
        }
        __syncthreads();
        #pragma unroll
        for (int ks = 0; ks < 2; ++ks) {
            bf16x8 a0 = *(const bf16x8*)&As[(wv * 32 + lr) * AP + ks * 32 + lq * 8];
            bf16x8 a1 = *(const bf16x8*)&As[(wv * 32 + 16 + lr) * AP + ks * 32 + lq * 8];
            #pragma unroll
            for (int nj = 0; nj < 4; ++nj) {
                bf16x8 b = *(const bf16x8*)&Bs[(nj * 16 + lr) * AP + ks * 32 + lq * 8];
                acc[0][nj] = __builtin_amdgcn_mfma_f32_16x16x32_bf16(a0, b, acc[0][nj], 0, 0, 0);
                acc[1][nj] = __builtin_amdgcn_mfma_f32_16x16x32_bf16(a1, b, acc[1][nj], 0, 0, 0);
            }
        }
        __syncthreads();
    }

    #pragma unroll
    for (int mi = 0; mi < 2; ++mi) {
        #pragma unroll
        for (int r = 0; r < 4; ++r) {
            int trow = m0 + wv * 32 + mi * 16 + lq * 4 + r;
            float* op = out + (size_t)trow * H_DIM + n0 + lr;
            #pragma unroll
            for (int nj = 0; nj < 4; ++nj)
                op[nj * 16] = acc[mi][nj][r];
        }
    }
}

// ---------------- combine: out[t] += sum_k dslot[slot(t,k)] ----------------
__global__ __launch_bounds__(256) void combine_kernel(
    const unsigned short* __restrict__ dslot, const int* __restrict__ tk_slot,
    float* __restrict__ out)
{
    const int t = blockIdx.x;
    const int c0 = threadIdx.x * 4;
    int slots[TOPK];
    #pragma unroll
    for (int k = 0; k < TOPK; ++k) slots[k] = tk_slot[t * TOPK + k];
    float4 o = *(float4*)(out + (size_t)t * H_DIM + c0);
    #pragma unroll
    for (int k = 0; k < TOPK; ++k) {
        uint2 v = *(const uint2*)(dslot + (size_t)slots[k] * H_DIM + c0);
        o.x += bf2f((unsigned short)(v.x & 0xffff));
        o.y += bf2f((unsigned short)(v.x >> 16));
        o.z += bf2f((unsigned short)(v.y & 0xffff));
        o.w += bf2f((unsigned short)(v.y >> 16));
    }
    *(float4*)(out + (size_t)t * H_DIM + c0) = o;
}

// ---------------- launch ----------------
extern "C" void kernel_launch(void* const* d_in, const int* in_sizes, int n_in,
                              void* d_out, int out_size, void* d_ws, size_t ws_size,
                              hipStream_t stream)
{
    const float* x  = (const float*)d_in[0];
    const float* gw = (const float*)d_in[1];
    const float* gb = (const float*)d_in[2];
    const float* Wg = (const float*)d_in[3];
    const float* Wu = (const float*)d_in[4];
    const float* Wd = (const float*)d_in[5];
    const float* Sg = (const float*)d_in[6];
    const float* Su = (const float*)d_in[7];
    const float* Sd = (const float*)d_in[8];
    float* out = (float*)d_out;

    const size_t NW  = (size_t)E_NUM * I_DIM * H_DIM;   // 46.1M per routed tensor
    const size_t NS  = (size_t)SI_DIM * H_DIM;          // 1.44M per shared tensor
    const size_t NX  = (size_t)T_TOK * H_DIM;           // 1M

    // base workspace (always used)
    unsigned short* act   = (unsigned short*)d_ws;                  // NSLOT*I_DIM
    unsigned short* sact  = act + (size_t)NSLOT * I_DIM;            // T*SI
    unsigned short* dslot = sact + (size_t)T_TOK * SI_DIM;          // NSLOT*H
    int* counts   = (int*)(dslot + (size_t)NSLOT * H_DIM);
    int* fillc    = counts + 64;
    int* offs     = fillc + 64;
    int* tk_idx   = offs + 64;
    float* tk_w   = (float*)(tk_idx + NSLOT);
    int* tok_list = (int*)(tk_w + NSLOT);
    float* w_list = (float*)(tok_list + NSLOT);
    int* tk_slot  = (int*)(w_list + NSLOT);
    size_t base_end = (size_t)((char*)(tk_slot + NSLOT) - (char*)d_ws);
    base_end = (base_end + 255) & ~(size_t)255;

    // conversion region (optional)
    size_t conv_bytes = (3 * NW + 3 * NS + NX) * sizeof(unsigned short);
    bool pre = (ws_size >= base_end + conv_bytes);

    unsigned short* bWg = (unsigned short*)((char*)d_ws + base_end);
    unsigned short* bWu = bWg + NW;
    unsigned short* bWd = bWu + NW;
    unsigned short* bSg = bWd + NW;
    unsigned short* bSu = bSg + NS;
    unsigned short* bSd = bSu + NS;
    unsigned short* xb  = bSd + NS;

    zero_kernel<<<1, 64, 0, stream>>>(counts, fillc);
    route_kernel<<<T_TOK, 64, 0, stream>>>(x, gw, gb, counts, tk_idx, tk_w);
    scan_kernel<<<1, 64, 0, stream>>>(counts, offs);
    fill_kernel<<<4, 256, 0, stream>>>(tk_idx, tk_w, offs, fillc, tok_list, w_list, tk_slot);

    if (pre) {
        cvt_kernel<<<2048, 256, 0, stream>>>(Wg, bWg, (int)(NW / 8));
        cvt_kernel<<<2048, 256, 0, stream>>>(Wu, bWu, (int)(NW / 8));
        cvt_kernel<<<2048, 256, 0, stream>>>(Wd, bWd, (int)(NW / 8));
        cvt_kernel<<<512, 256, 0, stream>>>(Sg, bSg, (int)(NS / 8));
        cvt_kernel<<<512, 256, 0, stream>>>(Su, bSu, (int)(NS / 8));
        cvt_kernel<<<512, 256, 0, stream>>>(Sd, bSd, (int)(NS / 8));
        cvt_kernel<<<512, 256, 0, stream>>>(x, xb, (int)(NX / 8));

        gateup_routed_mfma<true><<<dim3(11, 8, 64), 256, 0, stream>>>(
            x, xb, Wg, Wu, bWg, bWu, offs, counts, tok_list, w_list, act);
        gateup_shared_mfma<true><<<dim3(22, 8, 1), 256, 0, stream>>>(
            x, xb, Sg, Su, bSg, bSu, sact);
        down_shared_mfma<true><<<dim3(16, 8, 1), 256, 0, stream>>>(sact, Sd, bSd, out);
        down_routed_mfma<true><<<dim3(16, 8, 64), 256, 0, stream>>>(
            act, Wd, bWd, offs, counts, dslot);
    } else {
        gateup_routed_mfma<false><<<dim3(11, 8, 64), 256, 0, stream>>>(
            x, xb, Wg, Wu, bWg, bWu, offs, counts, tok_list, w_list, act);
        gateup_shared_mfma<false><<<dim3(22, 8, 1), 256, 0, stream>>>(
            x, xb, Sg, Su, bSg, bSu, sact);
        down_shared_mfma<false><<<dim3(16, 8, 1), 256, 0, stream>>>(sact, Sd, bSd, out);
        down_routed_mfma<false><<<dim3(16, 8, 64), 256, 0, stream>>>(
            act, Wd, bWd, offs, counts, dslot);
    }
    combine_kernel<<<T_TOK, 256, 0, stream>>>(dslot, tk_slot, out);
}